// Round 1
// baseline (11232.256 us; speedup 1.0000x reference)
//
#include <hip/hip_runtime.h>

#define T_ 512
#define B_ 256
#define H_ 256
#define DIN_ 64
#define CSTR 544   // ints per batch-group in cnt array (T_+1 used, padded)

typedef __attribute__((ext_vector_type(8))) short short8;
typedef __attribute__((ext_vector_type(4))) float f32x4;

__device__ __forceinline__ unsigned short f2bf(float f) {
  unsigned u = __float_as_uint(f);
  u += 0x7FFFu + ((u >> 16) & 1u);   // RNE
  return (unsigned short)(u >> 16);
}
__device__ __forceinline__ float bf2f(unsigned short s) {
  return __uint_as_float(((unsigned)s) << 16);
}
__device__ __forceinline__ float sigm(float x) { return 1.0f / (1.0f + __expf(-x)); }
__device__ __forceinline__ float tanh_(float x) {
  float xx = fminf(fmaxf(x, -30.0f), 30.0f);
  float e = __expf(2.0f * xx);
  return (e - 1.0f) / (e + 1.0f);
}

// Grid: 256 wgs x 256 threads. wg = gb*16 + gc.
//   gb: batch group (16 rows), gc: h-column group (16 cols -> 64 gate cols).
// Wave w (0..3) computes gate type w (i,f,g,o) as one 16x16 MFMA tile.
// W_ih/W_hh fragments are VGPR-resident for the whole kernel.
// h exchanged per step via agent-scope bf16 stores + per-(gb,step) flag counter.
__global__ __launch_bounds__(256) void lstm_kern(
    const float* __restrict__ xin, const float* __restrict__ h0f,
    const float* __restrict__ c0f, const float* __restrict__ Wih,
    const float* __restrict__ Whh, const float* __restrict__ bias,
    const float* __restrict__ Wout, const float* __restrict__ bout,
    float* __restrict__ out, unsigned short* hbuf, int* cnt)
{
  const int tid = threadIdx.x;
  const int wg  = blockIdx.x;
  const int gb  = wg >> 4;
  const int gc  = wg & 15;
  const int wv  = tid >> 6;   // wave = gate type
  const int ln  = tid & 63;
  const int colB = ln & 15;   // MFMA n / A-row m
  const int krow = ln >> 4;   // MFMA k-quad

  __shared__ unsigned short h_s[16 * 264];  // 16 rows x 256 bf16, pitch 264
  __shared__ unsigned short x_s[16 * 72];   // 16 rows x 64  bf16, pitch 72
  __shared__ float gbuf[4 * 16 * 17];       // [gate][row][col] padded

  // ---- load W fragments (B-operand layout: lane holds W[gate_row j][k=krow*8+i]) ----
  const int j = wv * H_ + gc * 16 + colB;   // row in [0,4H)
  short8 bh[8], bx[2];
  #pragma unroll
  for (int kc = 0; kc < 8; ++kc) {
    const float* p = Whh + j * H_ + kc * 32 + krow * 8;
    short8 f;
    #pragma unroll
    for (int i = 0; i < 8; ++i) f[i] = (short)f2bf(p[i]);
    bh[kc] = f;
  }
  #pragma unroll
  for (int kc = 0; kc < 2; ++kc) {
    const float* p = Wih + j * DIN_ + kc * 32 + krow * 8;
    short8 f;
    #pragma unroll
    for (int i = 0; i < 8; ++i) f[i] = (short)f2bf(p[i]);
    bx[kc] = f;
  }
  const float bval = bias[j];

  // elementwise mapping: thread owns (row er, h-col ec) of this wg's slice
  const int er = tid >> 4, ec = tid & 15;
  const int grow = gb * 16 + er;            // global batch row
  float c_val = c0f[grow * H_ + gc * 16 + ec];
  float h_val = 0.0f;

  for (int s = 1; s <= T_; ++s) {
    // stage x_{s-1} -> LDS bf16 (independent of h; overlaps the flag wait below)
    #pragma unroll
    for (int it = 0; it < 4; ++it) {
      int e = tid + it * 256;
      int r = e >> 6, d = e & 63;
      float v = xin[((gb * 16 + r) * T_ + (s - 1)) * DIN_ + d];
      x_s[r * 72 + d] = f2bf(v);
    }
    // wait for h^(s-1) from the 16 wgs of this batch group
    if (s > 1) {
      if (tid == 0) {
        int tries = 0;
        while (__hip_atomic_load(&cnt[gb * CSTR + (s - 1)],
                                 __ATOMIC_ACQUIRE, __HIP_MEMORY_SCOPE_AGENT) < 16) {
          if (++tries > (1 << 20)) break;   // hang guard
        }
      }
    }
    __syncthreads();
    // stage h^(s-1) -> LDS bf16
    if (s == 1) {
      #pragma unroll
      for (int it = 0; it < 4; ++it) {
        int e4 = tid + it * 256;
        int r = e4 >> 6, c4 = e4 & 63;
        const float4* p = (const float4*)(h0f + (gb * 16 + r) * H_) + c4;
        float4 v = *p;
        unsigned short* q = &h_s[r * 264 + c4 * 4];
        q[0] = f2bf(v.x); q[1] = f2bf(v.y); q[2] = f2bf(v.z); q[3] = f2bf(v.w);
      }
    } else {
      const unsigned long long* hb =
          (const unsigned long long*)(hbuf + ((s - 1) & 1) * (B_ * H_));
      #pragma unroll
      for (int it = 0; it < 4; ++it) {
        int e4 = tid + it * 256;
        int r = e4 >> 6, c4 = e4 & 63;
        unsigned long long v = __hip_atomic_load(&hb[(gb * 16 + r) * 64 + c4],
                                                 __ATOMIC_RELAXED, __HIP_MEMORY_SCOPE_AGENT);
        *(unsigned long long*)&h_s[r * 264 + c4 * 4] = v;
      }
    }
    __syncthreads();

    // ---- gates tile: D[batch m][gate col n], K = 64 (x) + 256 (h) ----
    f32x4 acc = {0.f, 0.f, 0.f, 0.f};
    #pragma unroll
    for (int kc = 0; kc < 2; ++kc) {
      short8 a = *(const short8*)&x_s[colB * 72 + kc * 32 + krow * 8];
      acc = __builtin_amdgcn_mfma_f32_16x16x32_bf16(a, bx[kc], acc, 0, 0, 0);
    }
    #pragma unroll
    for (int kc = 0; kc < 8; ++kc) {
      short8 a = *(const short8*)&h_s[colB * 264 + kc * 32 + krow * 8];
      acc = __builtin_amdgcn_mfma_f32_16x16x32_bf16(a, bh[kc], acc, 0, 0, 0);
    }
    #pragma unroll
    for (int i = 0; i < 4; ++i)   // D layout: col=lane&15, row=quad*4+i
      gbuf[wv * 272 + (krow * 4 + i) * 17 + colB] = acc[i] + bval;
    __syncthreads();

    // ---- elementwise LSTM cell update ----
    float gi = gbuf[0 * 272 + er * 17 + ec];
    float gf = gbuf[1 * 272 + er * 17 + ec];
    float gg = gbuf[2 * 272 + er * 17 + ec];
    float go = gbuf[3 * 272 + er * 17 + ec];
    c_val = sigm(gf) * c_val + sigm(gi) * tanh_(gg);
    h_val = sigm(go) * tanh_(c_val);

    // publish h slice (pack 2 bf16 per 4B agent store)
    unsigned hv = (unsigned)f2bf(h_val);
    unsigned ov = (unsigned)__shfl_xor((int)hv, 1, 64);
    if ((ec & 1) == 0) {
      unsigned packed = hv | (ov << 16);
      __hip_atomic_store(
          (unsigned*)(hbuf + (s & 1) * (B_ * H_) + grow * H_ + gc * 16 + ec),
          packed, __ATOMIC_RELAXED, __HIP_MEMORY_SCOPE_AGENT);
    }
    __threadfence();
    __syncthreads();
    if (tid == 0)
      __hip_atomic_fetch_add(&cnt[gb * CSTR + s], 1,
                             __ATOMIC_RELEASE, __HIP_MEMORY_SCOPE_AGENT);
  }

  // ---- outputs: rnn_outputs | logits | h | c ----
  const int gj = gc * 16 + ec;
  out[grow * H_ + gj] = h_val;                 // out0: rnn_outputs
  out[67584 + grow * H_ + gj] = h_val;         // out2: h   (65536+2048)
  out[133120 + grow * H_ + gj] = c_val;        // out3: c

  if (gc == 0) {  // logits for this batch group
    if (tid == 0) {
      int tries = 0;
      while (__hip_atomic_load(&cnt[gb * CSTR + T_],
                               __ATOMIC_ACQUIRE, __HIP_MEMORY_SCOPE_AGENT) < 16) {
        if (++tries > (1 << 20)) break;
      }
    }
    __syncthreads();
    const unsigned long long* hb =
        (const unsigned long long*)(hbuf + (T_ & 1) * (B_ * H_));
    #pragma unroll
    for (int it = 0; it < 4; ++it) {
      int e4 = tid + it * 256;
      int r = e4 >> 6, c4 = e4 & 63;
      unsigned long long v = __hip_atomic_load(&hb[(gb * 16 + r) * 64 + c4],
                                               __ATOMIC_RELAXED, __HIP_MEMORY_SCOPE_AGENT);
      *(unsigned long long*)&h_s[r * 264 + c4 * 4] = v;
    }
    __syncthreads();
    if (tid < 128) {
      int r = tid >> 3, o = tid & 7;
      float a = bout[o];
      for (int k = 0; k < H_; ++k)
        a = fmaf(bf2f(h_s[r * 264 + k]), Wout[o * H_ + k], a);
      out[65536 + (gb * 16 + r) * 8 + o] = a;   // out1: logits
    }
  }
}

extern "C" void kernel_launch(void* const* d_in, const int* in_sizes, int n_in,
                              void* d_out, int out_size, void* d_ws, size_t ws_size,
                              hipStream_t stream) {
  const float* xin  = (const float*)d_in[0];
  const float* h0f  = (const float*)d_in[1];
  const float* c0f  = (const float*)d_in[2];
  const float* Wih  = (const float*)d_in[3];
  const float* Whh  = (const float*)d_in[4];
  const float* bias = (const float*)d_in[5];
  const float* Wout = (const float*)d_in[6];
  const float* bout = (const float*)d_in[7];
  float* out = (float*)d_out;

  // ws layout: hbuf[2][256][256] bf16 (262144 B) | cnt[16][CSTR] int (34816 B)
  unsigned short* hbuf = (unsigned short*)d_ws;
  int* cnt = (int*)((char*)d_ws + 262144);
  hipMemsetAsync(cnt, 0, 16 * CSTR * sizeof(int), stream);

  void* args[] = {&xin, &h0f, &c0f, &Wih, &Whh, &bias, &Wout, &bout,
                  &out, &hbuf, &cnt};
  hipLaunchCooperativeKernel((void*)lstm_kern, dim3(256), dim3(256),
                             args, 0, stream);
}

// Round 2
// 2786.449 us; speedup vs baseline: 4.0310x; 4.0310x over previous
//
#include <hip/hip_runtime.h>

#define T_ 512
#define B_ 256
#define H_ 256
#define DIN_ 64
#define CSTR 544   // ints per batch-group in cnt array (T_+1 used, padded)

typedef __attribute__((ext_vector_type(8))) short short8;
typedef __attribute__((ext_vector_type(4))) float f32x4;

__device__ __forceinline__ unsigned short f2bf(float f) {
  unsigned u = __float_as_uint(f);
  u += 0x7FFFu + ((u >> 16) & 1u);   // RNE
  return (unsigned short)(u >> 16);
}
__device__ __forceinline__ float bf2f(unsigned short s) {
  return __uint_as_float(((unsigned)s) << 16);
}
__device__ __forceinline__ float sigm(float x) { return 1.0f / (1.0f + __expf(-x)); }
__device__ __forceinline__ float tanh_(float x) {
  float xx = fminf(fmaxf(x, -30.0f), 30.0f);
  float e = __expf(2.0f * xx);
  return (e - 1.0f) / (e + 1.0f);
}

// Grid: 256 wgs x 256 threads. wg = gb*16 + gc.
//   gb: batch group (16 rows), gc: h-column group (16 cols -> 64 gate cols).
// Wave w (0..3) computes gate type w (i,f,g,o) as one 16x16 MFMA tile.
// W_ih/W_hh fragments are VGPR-resident for the whole kernel.
//
// Sync design (R2): all h-data and flag traffic is agent-scope (sc1) atomics,
// i.e. LLC-coherent by construction. NO acquire polls (acquire = buffer_inv
// per iteration -> wiped local L2, was the R1 bottleneck), NO per-thread
// threadfence. __syncthreads() drains vmcnt(0) so all sc1 h-stores are acked
// at LLC before tid0's RELEASE fetch_add publishes the flag.
__global__ __launch_bounds__(256) void lstm_kern(
    const float* __restrict__ xin, const float* __restrict__ h0f,
    const float* __restrict__ c0f, const float* __restrict__ Wih,
    const float* __restrict__ Whh, const float* __restrict__ bias,
    const float* __restrict__ Wout, const float* __restrict__ bout,
    float* __restrict__ out, unsigned short* hbuf, int* cnt)
{
  const int tid = threadIdx.x;
  const int wg  = blockIdx.x;
  const int gb  = wg >> 4;
  const int gc  = wg & 15;
  const int wv  = tid >> 6;   // wave = gate type
  const int ln  = tid & 63;
  const int colB = ln & 15;   // MFMA n / A-row m
  const int krow = ln >> 4;   // MFMA k-quad

  __shared__ unsigned short h_s[16 * 264];  // 16 rows x 256 bf16, pitch 264
  __shared__ unsigned short x_s[16 * 72];   // 16 rows x 64  bf16, pitch 72
  __shared__ float gbuf[4 * 16 * 17];       // [gate][row][col] padded

  // ---- load W fragments (B-operand layout: lane holds W[gate_row j][k=krow*8+i]) ----
  const int j = wv * H_ + gc * 16 + colB;   // row in [0,4H)
  short8 bh[8], bx[2];
  #pragma unroll
  for (int kc = 0; kc < 8; ++kc) {
    const float* p = Whh + j * H_ + kc * 32 + krow * 8;
    short8 f;
    #pragma unroll
    for (int i = 0; i < 8; ++i) f[i] = (short)f2bf(p[i]);
    bh[kc] = f;
  }
  #pragma unroll
  for (int kc = 0; kc < 2; ++kc) {
    const float* p = Wih + j * DIN_ + kc * 32 + krow * 8;
    short8 f;
    #pragma unroll
    for (int i = 0; i < 8; ++i) f[i] = (short)f2bf(p[i]);
    bx[kc] = f;
  }
  const float bval = bias[j];

  // elementwise mapping: thread owns (row er, h-col ec) of this wg's slice
  const int er = tid >> 4, ec = tid & 15;
  const int grow = gb * 16 + er;            // global batch row
  float c_val = c0f[grow * H_ + gc * 16 + ec];
  float h_val = 0.0f;

  for (int s = 1; s <= T_; ++s) {
    // stage x_{s-1} -> LDS bf16 (independent of h; overlaps the flag wait below)
    #pragma unroll
    for (int it = 0; it < 4; ++it) {
      int e = tid + it * 256;
      int r = e >> 6, d = e & 63;
      float v = xin[((gb * 16 + r) * T_ + (s - 1)) * DIN_ + d];
      x_s[r * 72 + d] = f2bf(v);
    }
    // wait for h^(s-1) from the 16 wgs of this batch group.
    // RELAXED poll: sc1 read straight from LLC, no cache-maintenance ops.
    if (s > 1) {
      if (tid == 0) {
        int tries = 0;
        while (__hip_atomic_load(&cnt[gb * CSTR + (s - 1)],
                                 __ATOMIC_RELAXED, __HIP_MEMORY_SCOPE_AGENT) < 16) {
          if (++tries > (1 << 21)) break;   // hang guard
        }
      }
    }
    __syncthreads();
    // stage h^(s-1) -> LDS bf16
    if (s == 1) {
      #pragma unroll
      for (int it = 0; it < 4; ++it) {
        int e4 = tid + it * 256;
        int r = e4 >> 6, c4 = e4 & 63;
        const float4* p = (const float4*)(h0f + (gb * 16 + r) * H_) + c4;
        float4 v = *p;
        unsigned short* q = &h_s[r * 264 + c4 * 4];
        q[0] = f2bf(v.x); q[1] = f2bf(v.y); q[2] = f2bf(v.z); q[3] = f2bf(v.w);
      }
    } else {
      const unsigned long long* hb =
          (const unsigned long long*)(hbuf + ((s - 1) & 1) * (B_ * H_));
      #pragma unroll
      for (int it = 0; it < 4; ++it) {
        int e4 = tid + it * 256;
        int r = e4 >> 6, c4 = e4 & 63;
        unsigned long long v = __hip_atomic_load(&hb[(gb * 16 + r) * 64 + c4],
                                                 __ATOMIC_RELAXED, __HIP_MEMORY_SCOPE_AGENT);
        *(unsigned long long*)&h_s[r * 264 + c4 * 4] = v;
      }
    }
    __syncthreads();

    // ---- gates tile: D[batch m][gate col n], K = 64 (x) + 256 (h) ----
    f32x4 acc = {0.f, 0.f, 0.f, 0.f};
    #pragma unroll
    for (int kc = 0; kc < 2; ++kc) {
      short8 a = *(const short8*)&x_s[colB * 72 + kc * 32 + krow * 8];
      acc = __builtin_amdgcn_mfma_f32_16x16x32_bf16(a, bx[kc], acc, 0, 0, 0);
    }
    #pragma unroll
    for (int kc = 0; kc < 8; ++kc) {
      short8 a = *(const short8*)&h_s[colB * 264 + kc * 32 + krow * 8];
      acc = __builtin_amdgcn_mfma_f32_16x16x32_bf16(a, bh[kc], acc, 0, 0, 0);
    }
    #pragma unroll
    for (int i = 0; i < 4; ++i)   // D layout: col=lane&15, row=quad*4+i
      gbuf[wv * 272 + (krow * 4 + i) * 17 + colB] = acc[i] + bval;
    __syncthreads();

    // ---- elementwise LSTM cell update ----
    float gi = gbuf[0 * 272 + er * 17 + ec];
    float gf = gbuf[1 * 272 + er * 17 + ec];
    float gg = gbuf[2 * 272 + er * 17 + ec];
    float go = gbuf[3 * 272 + er * 17 + ec];
    c_val = sigm(gf) * c_val + sigm(gi) * tanh_(gg);
    h_val = sigm(go) * tanh_(c_val);

    // publish h slice (pack 2 bf16 per 4B agent/sc1 store -> lands at LLC)
    unsigned hv = (unsigned)f2bf(h_val);
    unsigned ov = (unsigned)__shfl_xor((int)hv, 1, 64);
    if ((ec & 1) == 0) {
      unsigned packed = hv | (ov << 16);
      __hip_atomic_store(
          (unsigned*)(hbuf + (s & 1) * (B_ * H_) + grow * H_ + gc * 16 + ec),
          packed, __ATOMIC_RELAXED, __HIP_MEMORY_SCOPE_AGENT);
    }
    // __syncthreads() drains vmcnt(0) in every wave -> all sc1 stores acked
    // at LLC before the flag below is published.
    __syncthreads();
    if (tid == 0)
      __hip_atomic_fetch_add(&cnt[gb * CSTR + s], 1,
                             __ATOMIC_RELEASE, __HIP_MEMORY_SCOPE_AGENT);
  }

  // ---- outputs: rnn_outputs | logits | h | c ----
  const int gj = gc * 16 + ec;
  out[grow * H_ + gj] = h_val;                 // out0: rnn_outputs
  out[67584 + grow * H_ + gj] = h_val;         // out2: h   (65536+2048)
  out[133120 + grow * H_ + gj] = c_val;        // out3: c

  if (gc == 0) {  // logits for this batch group
    if (tid == 0) {
      int tries = 0;
      while (__hip_atomic_load(&cnt[gb * CSTR + T_],
                               __ATOMIC_RELAXED, __HIP_MEMORY_SCOPE_AGENT) < 16) {
        if (++tries > (1 << 21)) break;
      }
    }
    __syncthreads();
    const unsigned long long* hb =
        (const unsigned long long*)(hbuf + (T_ & 1) * (B_ * H_));
    #pragma unroll
    for (int it = 0; it < 4; ++it) {
      int e4 = tid + it * 256;
      int r = e4 >> 6, c4 = e4 & 63;
      unsigned long long v = __hip_atomic_load(&hb[(gb * 16 + r) * 64 + c4],
                                               __ATOMIC_RELAXED, __HIP_MEMORY_SCOPE_AGENT);
      *(unsigned long long*)&h_s[r * 264 + c4 * 4] = v;
    }
    __syncthreads();
    if (tid < 128) {
      int r = tid >> 3, o = tid & 7;
      float a = bout[o];
      for (int k = 0; k < H_; ++k)
        a = fmaf(bf2f(h_s[r * 264 + k]), Wout[o * H_ + k], a);
      out[65536 + (gb * 16 + r) * 8 + o] = a;   // out1: logits
    }
  }
}

extern "C" void kernel_launch(void* const* d_in, const int* in_sizes, int n_in,
                              void* d_out, int out_size, void* d_ws, size_t ws_size,
                              hipStream_t stream) {
  const float* xin  = (const float*)d_in[0];
  const float* h0f  = (const float*)d_in[1];
  const float* c0f  = (const float*)d_in[2];
  const float* Wih  = (const float*)d_in[3];
  const float* Whh  = (const float*)d_in[4];
  const float* bias = (const float*)d_in[5];
  const float* Wout = (const float*)d_in[6];
  const float* bout = (const float*)d_in[7];
  float* out = (float*)d_out;

  // ws layout: hbuf[2][256][256] bf16 (262144 B) | cnt[16][CSTR] int (34816 B)
  unsigned short* hbuf = (unsigned short*)d_ws;
  int* cnt = (int*)((char*)d_ws + 262144);
  hipMemsetAsync(cnt, 0, 16 * CSTR * sizeof(int), stream);

  void* args[] = {&xin, &h0f, &c0f, &Wih, &Whh, &bias, &Wout, &bout,
                  &out, &hbuf, &cnt};
  hipLaunchCooperativeKernel((void*)lstm_kern, dim3(256), dim3(256),
                             args, 0, stream);
}